// Round 7
// baseline (188.065 us; speedup 1.0000x reference)
//
#include <hip/hip_runtime.h>
#include <hip/hip_bf16.h>

typedef short bf16x8 __attribute__((ext_vector_type(8)));  // 8 bf16 (4 VGPRs)
typedef float f32x4 __attribute__((ext_vector_type(4)));

#define S_LEN 2048
#define NHEAD 16
#define DM 1024

#if __has_builtin(__builtin_amdgcn_exp2f)
#define EXP2(x) __builtin_amdgcn_exp2f(x)
#else
#define EXP2(x) exp2f(x)
#endif

__device__ __forceinline__ short f2bf(float f) {
  union { float f; unsigned u; } x; x.f = f;
  unsigned r = x.u + 0x7fffu + ((x.u >> 16) & 1u);  // RNE
  return (short)(r >> 16);
}

// v_cvt_pk_bf16_f32: lo -> bits[15:0], hi -> bits[31:16], RNE
__device__ __forceinline__ unsigned cvt_pk_bf16(float lo, float hi) {
  unsigned r;
  asm("v_cvt_pk_bf16_f32 %0, %1, %2" : "=v"(r) : "v"(lo), "v"(hi));
  return r;
}

__device__ __forceinline__ void pl32swap(unsigned& a, unsigned& b) {
#if __has_builtin(__builtin_amdgcn_permlane32_swap)
  auto r = __builtin_amdgcn_permlane32_swap(a, b, false, false);
  a = r[0]; b = r[1];
#else
  asm volatile("v_permlane32_swap_b32 %0, %1" : "+v"(a), "+v"(b));
#endif
}
__device__ __forceinline__ void pl16swap(unsigned& a, unsigned& b) {
#if __has_builtin(__builtin_amdgcn_permlane16_swap)
  auto r = __builtin_amdgcn_permlane16_swap(a, b, false, false);
  a = r[0]; b = r[1];
#else
  asm volatile("v_permlane16_swap_b32 %0, %1" : "+v"(a), "+v"(b));
#endif
}

__device__ __forceinline__ void gload16(const void* g, void* l) {
  __builtin_amdgcn_global_load_lds(
      (const __attribute__((address_space(1))) void*)g,
      (__attribute__((address_space(3))) void*)l, 16, 0, 0);
}

// ---------------- weight transpose+convert: T[n][k] = bf16(W[k][n]), 1024x1024
__global__ __launch_bounds__(256) void wtrans(const float* __restrict__ Wq, const float* __restrict__ Wk,
                                              const float* __restrict__ Wv, const float* __restrict__ Wo,
                                              short* Tq, short* Tk, short* Tv, short* To) {
  const int z = blockIdx.z;
  const float* W = (z == 0) ? Wq : (z == 1) ? Wk : (z == 2) ? Wv : Wo;
  short* T = (z == 0) ? Tq : (z == 1) ? Tk : (z == 2) ? Tv : To;
  __shared__ short Tl[64][72];
  const int tid = threadIdx.x;
  const int k0 = blockIdx.x * 64, n0 = blockIdx.y * 64;
  const int r = tid >> 2, c0 = (tid & 3) * 16;
#pragma unroll
  for (int j = 0; j < 4; j++) {
    float4 v = *(const float4*)&W[(size_t)(k0 + r) * DM + n0 + c0 + 4 * j];
    Tl[r][c0 + 4 * j + 0] = f2bf(v.x);
    Tl[r][c0 + 4 * j + 1] = f2bf(v.y);
    Tl[r][c0 + 4 * j + 2] = f2bf(v.z);
    Tl[r][c0 + 4 * j + 3] = f2bf(v.w);
  }
  __syncthreads();
  bf16x8 o0, o1;
#pragma unroll
  for (int j = 0; j < 8; j++) { o0[j] = Tl[c0 + j][r]; o1[j] = Tl[c0 + 8 + j][r]; }
  *(bf16x8*)&T[(size_t)(n0 + r) * DM + k0 + c0] = o0;
  *(bf16x8*)&T[(size_t)(n0 + r) * DM + k0 + c0 + 8] = o1;
}

// ---------------- gemm4: fused QKV projection, single launch.
// A = query/key/value (f32, selected per block), B = Wt bf16 [3072][1024]
// (concatenated WqT|WkT|WvT). BM=128 BN=64 BK=64, 256 thr (4 waves 2x2).
// A: reg-staged + converted, single-buffer LDS; B: gload16, double-buffered.
// which=0 -> Qb (scaled 0.125*log2e), 1 -> Kb, 2 -> VbT (transposed scatter).
__global__ __launch_bounds__(256) void gemm4(const float* __restrict__ xq, const float* __restrict__ xk,
                                             const float* __restrict__ xv, const short* __restrict__ Wt,
                                             short* __restrict__ Qb, short* __restrict__ Kb,
                                             short* __restrict__ VbT) {
  __shared__ __align__(16) short Al[128 * 64];
  __shared__ __align__(16) short Bl[2][64 * 64];
  const int tid = threadIdx.x;
  const int lane = tid & 63, w = tid >> 6;
  const int wm = w >> 1, wn = w & 1;
  const int lr = lane & 15, g = lane >> 4;

  // XCD-chunked bijective swizzle over 1536 blocks (grid 48 x 32)
  const int flat = blockIdx.y * gridDim.x + blockIdx.x;
  const int wid = (flat & 7) * 192 + (flat >> 3);
  const int bx = wid % 48, by = wid / 48;
  const int n0 = bx * 64, m0 = by * 128;
  const int which = n0 >> 10;
  const float* A = (which == 0) ? xq : (which == 1) ? xk : xv;

  f32x4 acc[4][2];
#pragma unroll
  for (int i = 0; i < 4; i++)
#pragma unroll
    for (int j = 0; j < 2; j++) acc[i][j] = (f32x4){0.f, 0.f, 0.f, 0.f};

  // A reg-stage: 2 threads/row, 32 f32 each
  const int ar = tid >> 1, ac = (tid & 1) * 32;
  float4 la[8];
  // B staging geometry (gload16, swizzled source)
  const int srow = lane >> 3;
  const int sch = (lane & 7) ^ (srow & 7);
  const short* gB = Wt + (size_t)(n0 + w * 16 + srow) * 1024 + 8 * sch;

#define LOADA4(kk)                                                                  \
  do {                                                                              \
    _Pragma("unroll") for (int j = 0; j < 8; j++)                                   \
        la[j] = *(const float4*)&A[(size_t)(m0 + ar) * 1024 + (kk) + ac + 4 * j];   \
  } while (0)
#define STAGEB(buf, kk)                                                             \
  do {                                                                              \
    _Pragma("unroll") for (int c = 0; c < 2; c++)                                   \
        gload16(gB + (size_t)c * 8 * 1024 + (kk), &Bl[buf][(w * 16 + c * 8) * 64]); \
  } while (0)

  const int nsteps = 16;  // K=1024 / 64
  LOADA4(0);
  STAGEB(0, 0);
  int buf = 0;
  for (int t = 0; t < nsteps; t++) {
    __syncthreads();  // (a) prev compute done; Bl[buf] resident (vmcnt drained); la landed
    // write A regs -> LDS (swizzled chunks)
#pragma unroll
    for (int j = 0; j < 4; j++) {
      float4 v0 = la[2 * j], v1 = la[2 * j + 1];
      bf16x8 tt;
      tt[0] = f2bf(v0.x); tt[1] = f2bf(v0.y); tt[2] = f2bf(v0.z); tt[3] = f2bf(v0.w);
      tt[4] = f2bf(v1.x); tt[5] = f2bf(v1.y); tt[6] = f2bf(v1.z); tt[7] = f2bf(v1.w);
      *(bf16x8*)&Al[ar * 64 + 8 * (((ac >> 3) + j) ^ (ar & 7))] = tt;
    }
    __syncthreads();  // (b) Al visible; no outstanding vmem here
    if (t + 1 < nsteps) { STAGEB(buf ^ 1, (t + 1) << 6); LOADA4((t + 1) << 6); }
#pragma unroll
    for (int kc = 0; kc < 2; kc++) {
      bf16x8 af[4], bfr[2];
#pragma unroll
      for (int mt = 0; mt < 4; mt++) {
        int row = wm * 64 + mt * 16 + lr;
        af[mt] = *(const bf16x8*)&Al[row * 64 + 8 * ((kc * 4 + g) ^ (lr & 7))];
      }
#pragma unroll
      for (int nt = 0; nt < 2; nt++) {
        int row = wn * 32 + nt * 16 + lr;
        bfr[nt] = *(const bf16x8*)&Bl[buf][row * 64 + 8 * ((kc * 4 + g) ^ (lr & 7))];
      }
      __builtin_amdgcn_s_setprio(1);
#pragma unroll
      for (int mt = 0; mt < 4; mt++)
#pragma unroll
        for (int nt = 0; nt < 2; nt++)
          acc[mt][nt] = __builtin_amdgcn_mfma_f32_16x16x32_bf16(af[mt], bfr[nt], acc[mt][nt], 0, 0, 0);
      __builtin_amdgcn_s_setprio(0);
    }
    buf ^= 1;
  }
#undef LOADA4
#undef STAGEB

  const int hcol = (n0 >> 6) & 15;
#pragma unroll
  for (int mt = 0; mt < 4; mt++)
#pragma unroll
    for (int nt = 0; nt < 2; nt++) {
      const int d = wn * 32 + nt * 16 + lr;
      if (which == 2) {
        const int sb = m0 + wm * 64 + mt * 16 + g * 4;
        const int bb = sb >> 11, s = sb & (S_LEN - 1);
        union { short s4[4]; uint2 u; } pk;
#pragma unroll
        for (int r = 0; r < 4; r++) pk.s4[r] = f2bf(acc[mt][nt][r]);
        *(uint2*)&VbT[(((size_t)(bb * NHEAD + hcol)) * 64 + d) * S_LEN + s] = pk.u;
      } else {
        short* dst = (which == 0) ? Qb : Kb;
        const float scale = (which == 0) ? 0.18033688011f : 1.f;
#pragma unroll
        for (int r = 0; r < 4; r++) {
          int row = m0 + wm * 64 + mt * 16 + g * 4 + r;
          int bb = row >> 11, s = row & (S_LEN - 1);
          dst[(((size_t)(bb * NHEAD + hcol)) * S_LEN + s) * 64 + d] = f2bf(acc[mt][nt][r] * scale);
        }
      }
    }
}

// ---------------- gemm3: all-bf16, global_load_lds dbuf, swizzled LDS,
// XCD-chunked block swizzle. C(MxN) = A(MxK) @ Bt^T. Used for Wo.
template<int CM>
__global__ __launch_bounds__(256) void gemm3(const short* __restrict__ A, const short* __restrict__ Bt,
                                             void* __restrict__ Cp, int M, int N, int K) {
  __shared__ __align__(16) short Al[2][128 * 64];
  __shared__ __align__(16) short Bl[2][64 * 64];
  const int tid = threadIdx.x;
  const int lane = tid & 63, w = tid >> 6;
  const int wm = w >> 1, wn = w & 1;
  const int lr = lane & 15, g = lane >> 4;

  const int flat = blockIdx.y * gridDim.x + blockIdx.x;
  const int nwg = gridDim.x * gridDim.y;
  const int wid = (flat & 7) * (nwg >> 3) + (flat >> 3);
  const int bx = wid % gridDim.x, by = wid / gridDim.x;
  const int m0 = by * 128, n0 = bx * 64;

  f32x4 acc[4][2];
#pragma unroll
  for (int i = 0; i < 4; i++)
#pragma unroll
    for (int j = 0; j < 2; j++) acc[i][j] = (f32x4){0.f, 0.f, 0.f, 0.f};

  const int srow = lane >> 3;
  const int sch = (lane & 7) ^ (srow & 7);
  const short* gA = A + (size_t)(m0 + w * 32 + srow) * K + 8 * sch;
  const short* gB = Bt + (size_t)(n0 + w * 16 + srow) * K + 8 * sch;

#define STAGE(buf, kk)                                                              \
  do {                                                                              \
    _Pragma("unroll") for (int c = 0; c < 4; c++)                                   \
        gload16(gA + (size_t)c * 8 * K + (kk), &Al[buf][(w * 32 + c * 8) * 64]);    \
    _Pragma("unroll") for (int c = 0; c < 2; c++)                                   \
        gload16(gB + (size_t)c * 8 * K + (kk), &Bl[buf][(w * 16 + c * 8) * 64]);    \
  } while (0)

  const int nsteps = K >> 6;
  STAGE(0, 0);
  int buf = 0;
  for (int t = 0; t < nsteps; t++) {
    __syncthreads();
    if (t + 1 < nsteps) STAGE(buf ^ 1, (t + 1) << 6);
#pragma unroll
    for (int kc = 0; kc < 2; kc++) {
      bf16x8 af[4], bfr[2];
#pragma unroll
      for (int mt = 0; mt < 4; mt++) {
        int row = wm * 64 + mt * 16 + lr;
        af[mt] = *(const bf16x8*)&Al[buf][row * 64 + 8 * ((kc * 4 + g) ^ (lr & 7))];
      }
#pragma unroll
      for (int nt = 0; nt < 2; nt++) {
        int row = wn * 32 + nt * 16 + lr;
        bfr[nt] = *(const bf16x8*)&Bl[buf][row * 64 + 8 * ((kc * 4 + g) ^ (lr & 7))];
      }
      __builtin_amdgcn_s_setprio(1);
#pragma unroll
      for (int mt = 0; mt < 4; mt++)
#pragma unroll
        for (int nt = 0; nt < 2; nt++)
          acc[mt][nt] = __builtin_amdgcn_mfma_f32_16x16x32_bf16(af[mt], bfr[nt], acc[mt][nt], 0, 0, 0);
      __builtin_amdgcn_s_setprio(0);
    }
    buf ^= 1;
  }
#undef STAGE

#pragma unroll
  for (int mt = 0; mt < 4; mt++)
#pragma unroll
    for (int nt = 0; nt < 2; nt++)
#pragma unroll
      for (int r = 0; r < 4; r++) {
        int row = m0 + wm * 64 + mt * 16 + g * 4 + r;
        int col = n0 + wn * 32 + nt * 16 + lr;
        if (CM == 0) {
          ((float*)Cp)[(size_t)row * N + col] = acc[mt][nt][r];
        } else if (CM == 1 || CM == 3) {
          float v = (CM == 3) ? acc[mt][nt][r] * 0.18033688011f : acc[mt][nt][r];
          int b = row >> 11, s = row & (S_LEN - 1);
          int h = col >> 6, d = col & 63;
          ((short*)Cp)[(((size_t)(b * NHEAD + h)) * S_LEN + s) * 64 + d] = f2bf(v);
        } else {
          int h = row >> 6, d = row & 63;
          int b = col >> 11, s = col & (S_LEN - 1);
          ((short*)Cp)[(((size_t)(b * NHEAD + h)) * 64 + d) * S_LEN + s] = f2bf(acc[mt][nt][r]);
        }
      }
}

// ---------------- gemm2 (reg-staged, fallback path for small ws)
template<int AM, int BMODE, int CM>
__global__ __launch_bounds__(256) void gemm2(const void* __restrict__ Ap, const void* __restrict__ Bp,
                                             void* __restrict__ Cp, int M, int N, int K) {
  __shared__ __align__(16) short Al[128][72];
  __shared__ __align__(16) short Bl[64][72];
  const int tid = threadIdx.x;
  const int lane = tid & 63, w = tid >> 6;
  const int wm = w >> 1, wn = w & 1;
  const int lr = lane & 15, g = lane >> 4;
  const int m0 = blockIdx.y * 128, n0 = blockIdx.x * 64;

  f32x4 acc[4][2];
#pragma unroll
  for (int i = 0; i < 4; i++)
#pragma unroll
    for (int j = 0; j < 2; j++) acc[i][j] = (f32x4){0.f, 0.f, 0.f, 0.f};

  const int ar = tid >> 1, ac = (tid & 1) * 32;
  const int br = tid >> 2, bc = (tid & 3) * 16;

  float4 la[8]; bf16x8 la8[4];
  float4 lb[4]; bf16x8 lb8[2];

#define LOADA(kk)                                                                        \
  do {                                                                                   \
    if (AM == 0) {                                                                       \
      const float* A = (const float*)Ap;                                                 \
      _Pragma("unroll") for (int j = 0; j < 8; j++)                                      \
          la[j] = *(const float4*)&A[(size_t)(m0 + ar) * K + (kk) + ac + 4 * j];         \
    } else {                                                                             \
      const short* A = (const short*)Ap;                                                 \
      _Pragma("unroll") for (int j = 0; j < 4; j++)                                      \
          la8[j] = *(const bf16x8*)&A[(size_t)(m0 + ar) * K + (kk) + ac + 8 * j];        \
    }                                                                                    \
  } while (0)

#define LOADB(kk)                                                                        \
  do {                                                                                   \
    if (BMODE == 0) {                                                                    \
      const float* B = (const float*)Bp;                                                 \
      _Pragma("unroll") for (int j = 0; j < 4; j++)                                      \
          lb[j] = *(const float4*)&B[(size_t)(n0 + br) * K + (kk) + bc + 4 * j];         \
    } else if (BMODE == 1) {                                                             \
      const short* B = (const short*)Bp;                                                 \
      _Pragma("unroll") for (int j = 0; j < 2; j++)                                      \
          lb8[j] = *(const bf16x8*)&B[(size_t)(n0 + br) * K + (kk) + bc + 8 * j];        \
    } else {                                                                             \
      const float* B = (const float*)Bp;                                                 \
      _Pragma("unroll") for (int j = 0; j < 4; j++)                                      \
          lb[j] = *(const float4*)&B[(size_t)((kk) + br) * N + n0 + bc + 4 * j];         \
    }                                                                                    \
  } while (0)

  const int nsteps = K >> 6;
  LOADA(0); LOADB(0);

  for (int t = 0; t < nsteps; t++) {
    __syncthreads();
    if (AM == 0) {
#pragma unroll
      for (int j = 0; j < 4; j++) {
        float4 v0 = la[2 * j], v1 = la[2 * j + 1];
        bf16x8 tt;
        tt[0] = f2bf(v0.x); tt[1] = f2bf(v0.y); tt[2] = f2bf(v0.z); tt[3] = f2bf(v0.w);
        tt[4] = f2bf(v1.x); tt[5] = f2bf(v1.y); tt[6] = f2bf(v1.z); tt[7] = f2bf(v1.w);
        *(bf16x8*)&Al[ar][ac + 8 * j] = tt;
      }
    } else {
#pragma unroll
      for (int j = 0; j < 4; j++) *(bf16x8*)&Al[ar][ac + 8 * j] = la8[j];
    }
    if (BMODE == 0) {
#pragma unroll
      for (int j = 0; j < 2; j++) {
        float4 v0 = lb[2 * j], v1 = lb[2 * j + 1];
        bf16x8 tt;
        tt[0] = f2bf(v0.x); tt[1] = f2bf(v0.y); tt[2] = f2bf(v0.z); tt[3] = f2bf(v0.w);
        tt[4] = f2bf(v1.x); tt[5] = f2bf(v1.y); tt[6] = f2bf(v1.z); tt[7] = f2bf(v1.w);
        *(bf16x8*)&Bl[br][bc + 8 * j] = tt;
      }
    } else if (BMODE == 1) {
#pragma unroll
      for (int j = 0; j < 2; j++) *(bf16x8*)&Bl[br][bc + 8 * j] = lb8[j];
    } else {
#pragma unroll
      for (int j = 0; j < 4; j++) {
        float4 v = lb[j];
        Bl[bc + 4 * j + 0][br] = f2bf(v.x);
        Bl[bc + 4 * j + 1][br] = f2bf(v.y);
        Bl[bc + 4 * j + 2][br] = f2bf(v.z);
        Bl[bc + 4 * j + 3][br] = f2bf(v.w);
      }
    }
    __syncthreads();
    if (t + 1 < nsteps) { LOADA((t + 1) << 6); LOADB((t + 1) << 6); }
#pragma unroll
    for (int kc = 0; kc < 2; kc++) {
      bf16x8 af[4], bfr[2];
#pragma unroll
      for (int mt = 0; mt < 4; mt++) af[mt] = *(const bf16x8*)&Al[wm * 64 + mt * 16 + lr][kc * 32 + g * 8];
#pragma unroll
      for (int nt = 0; nt < 2; nt++) bfr[nt] = *(const bf16x8*)&Bl[wn * 32 + nt * 16 + lr][kc * 32 + g * 8];
#pragma unroll
      for (int mt = 0; mt < 4; mt++)
#pragma unroll
        for (int nt = 0; nt < 2; nt++)
          acc[mt][nt] = __builtin_amdgcn_mfma_f32_16x16x32_bf16(af[mt], bfr[nt], acc[mt][nt], 0, 0, 0);
    }
  }
#undef LOADA
#undef LOADB

#pragma unroll
  for (int mt = 0; mt < 4; mt++)
#pragma unroll
    for (int nt = 0; nt < 2; nt++)
#pragma unroll
      for (int r = 0; r < 4; r++) {
        int row = m0 + wm * 64 + mt * 16 + g * 4 + r;
        int col = n0 + wn * 32 + nt * 16 + lr;
        if (CM == 0) {
          ((float*)Cp)[(size_t)row * N + col] = acc[mt][nt][r];
        } else if (CM == 1 || CM == 3) {
          float v = (CM == 3) ? acc[mt][nt][r] * 0.18033688011f : acc[mt][nt][r];
          int b = row >> 11, s = row & (S_LEN - 1);
          int h = col >> 6, d = col & 63;
          ((short*)Cp)[(((size_t)(b * NHEAD + h)) * S_LEN + s) * 64 + d] = f2bf(v);
        } else {
          int h = row >> 6, d = row & 63;
          int b = col >> 11, s = col & (S_LEN - 1);
          ((short*)Cp)[(((size_t)(b * NHEAD + h)) * 64 + d) * S_LEN + s] = f2bf(acc[mt][nt][r]);
        }
      }
}

// ---------------- Flash attention v7: QBLK=64 (4 waves x 16 q), 1024 blocks
// = 4 blocks/CU (4 waves/SIMD). Swapped QK^T + in-register P (permlane),
// max-free exp2 softmax (Q pre-scaled 0.125*log2e), deferred row-sum.
// Q,K: [bh][s][64] bf16.  V^T: [bh][64][s] bf16.
__global__ __launch_bounds__(256, 4) void attn7(const short* __restrict__ Qb,
                                                const short* __restrict__ Kb,
                                                const short* __restrict__ VbT,
                                                const int* __restrict__ mask,
                                                short* __restrict__ Ob) {
  __shared__ __align__(16) short Kl[2][64][64];
  __shared__ __align__(16) short Vl[2][64][64];

  const int tid = threadIdx.x;
  const int lane = tid & 63, w = tid >> 6;  // 4 waves
  const int lr = lane & 15, g = lane >> 4;

  // XCD-chunked bijective swizzle: 1024 blocks, 128/XCD -> 4 heads/XCD
  const int flat = blockIdx.y * gridDim.x + blockIdx.x;
  const int wid = (flat & 7) * 128 + (flat >> 3);
  const int qblk = wid & 31, bh = wid >> 5;
  const int b = bh >> 4, h = bh & 15;
  const int qbase = qblk * 64;
  const size_t hoff = (size_t)bh * S_LEN * 64;

  bf16x8 qf[2];
#pragma unroll
  for (int kh = 0; kh < 2; kh++)
    qf[kh] = *(const bf16x8*)&Qb[hoff + (size_t)(qbase + w * 16 + lr) * 64 + kh * 32 + g * 8];

  f32x4 o_acc[4];
  float lsum = 0.f;
#pragma unroll
  for (int dg = 0; dg < 4; dg++) o_acc[dg] = (f32x4){0.f, 0.f, 0.f, 0.f};

  const int* maskb = mask + b * S_LEN;
  const int srow = lane >> 3;
  const int sch = (lane & 7) ^ (srow & 7);
  const short* gK = Kb + hoff + (size_t)(w * 16 + srow) * 64 + 8 * sch;
  const short* gV = VbT + hoff + (size_t)(w * 16 + srow) * S_LEN + 8 * sch;

#define STAGEKV(buf, kb)                                                         \
  do {                                                                           \
    _Pragma("unroll") for (int c = 0; c < 2; c++)                                \
        gload16(gK + (size_t)(kb + c * 8) * 64, &Kl[buf][w * 16 + c * 8][0]);    \
    _Pragma("unroll") for (int c = 0; c < 2; c++)                                \
        gload16(gV + (size_t)c * 8 * S_LEN + (kb), &Vl[buf][w * 16 + c * 8][0]); \
  } while (0)

  const int NT = S_LEN / 64;
  STAGEKV(0, 0);
  int buf = 0;

  for (int t = 0; t < NT; t++) {
    const int kb = t * 64;
    __syncthreads();  // vmcnt drained: tile t resident; prior reads of buf^1 done
    if (t + 1 < NT) STAGEKV(buf ^ 1, kb + 64);

    // mask bias for k = nt*16 + 4g + r
    float bias[4][4];
#pragma unroll
    for (int nt = 0; nt < 4; nt++) {
      int4 mv = *(const int4*)&maskb[kb + nt * 16 + 4 * g];
      bias[nt][0] = mv.x ? 0.f : -1e30f;
      bias[nt][1] = mv.y ? 0.f : -1e30f;
      bias[nt][2] = mv.z ? 0.f : -1e30f;
      bias[nt][3] = mv.w ? 0.f : -1e30f;
    }

    // ---- swapped QK^T: S^T = mfma(K, Q); lane holds P[q=lr][k=nt*16+4g+r]
    f32x4 s[4];
#pragma unroll
    for (int nt = 0; nt < 4; nt++) s[nt] = (f32x4){0.f, 0.f, 0.f, 0.f};
    __builtin_amdgcn_s_setprio(1);
#pragma unroll
    for (int nt = 0; nt < 4; nt++) {
      bf16x8 k0 = *(const bf16x8*)&Kl[buf][nt * 16 + lr][8 * (g ^ (lr & 7))];
      bf16x8 k1 = *(const bf16x8*)&Kl[buf][nt * 16 + lr][8 * ((4 + g) ^ (lr & 7))];
      s[nt] = __builtin_amdgcn_mfma_f32_16x16x32_bf16(k0, qf[0], s[nt], 0, 0, 0);
      s[nt] = __builtin_amdgcn_mfma_f32_16x16x32_bf16(k1, qf[1], s[nt], 0, 0, 0);
    }
    __builtin_amdgcn_s_setprio(0);

    // ---- softmax + pack
    unsigned W0[4], W1[4];
#pragma unroll
    for (int nt = 0; nt < 4; nt++) {
      float p0 = EXP2(s[nt][0] + bias[nt][0]);
      float p1 = EXP2(s[nt][1] + bias[nt][1]);
      float p2 = EXP2(s[nt][2] + bias[nt][2]);
      float p3 = EXP2(s[nt][3] + bias[nt][3]);
      lsum += (p0 + p1) + (p2 + p3);
      W0[nt] = cvt_pk_bf16(p0, p1);
      W1[nt] = cvt_pk_bf16(p2, p3);
    }

    // ---- in-register P redistribution to A-frag layout
    bf16x8 pf[2];
#pragma unroll
    for (int kh = 0; kh < 2; kh++) {
      unsigned a0 = W0[2 * kh], b0 = W0[2 * kh + 1];
      unsigned a1 = W1[2 * kh], b1 = W1[2 * kh + 1];
      pl32swap(a0, b0); pl16swap(a0, b0);
      pl32swap(a1, b1); pl16swap(a1, b1);
      union { unsigned u[4]; bf16x8 v; } pk;
      pk.u[0] = a0; pk.u[1] = a1; pk.u[2] = b0; pk.u[3] = b1;
      pf[kh] = pk.v;
    }

    // ---- PV
    __builtin_amdgcn_s_setprio(1);
#pragma unroll
    for (int dg = 0; dg < 4; dg++) {
      bf16x8 v0 = *(const bf16x8*)&Vl[buf][dg * 16 + lr][8 * (g ^ (lr & 7))];
      bf16x8 v1 = *(const bf16x8*)&Vl[buf][dg * 16 + lr][8 * ((4 + g) ^ (lr & 7))];
      o_acc[dg] = __builtin_amdgcn_mfma_f32_16x16x32_bf16(pf[0], v0, o_acc[dg], 0, 0, 0);
      o_acc[dg] = __builtin_amdgcn_mfma_f32_16x16x32_bf16(pf[1], v1, o_acc[dg], 0, 0, 0);
    }
    __builtin_amdgcn_s_setprio(0);
    buf ^= 1;
  }
#undef STAGEKV

  // ---- epilogue: lsum per lane covers q=lr; reduce over g, transpose to q=4g+r
  {
    float l = lsum;
    l += __shfl_xor(l, 16);
    l += __shfl_xor(l, 32);
    float inv = 1.f / l;
    float invq[4];
#pragma unroll
    for (int r = 0; r < 4; r++) invq[r] = __shfl(inv, 4 * g + r);
#pragma unroll
    for (int dg = 0; dg < 4; dg++)
#pragma unroll
      for (int r = 0; r < 4; r++) {
        int qr = qbase + w * 16 + 4 * g + r;
        int col = h * 64 + dg * 16 + lr;
        Ob[((size_t)b * S_LEN + qr) * DM + col] = f2bf(o_acc[dg][r] * invq[r]);
      }
  }
}

extern "C" void kernel_launch(void* const* d_in, const int* in_sizes, int n_in,
                              void* d_out, int out_size, void* d_ws, size_t ws_size,
                              hipStream_t stream) {
  const float* query = (const float*)d_in[0];
  const float* key   = (const float*)d_in[1];
  const float* value = (const float*)d_in[2];
  const float* Wq = (const float*)d_in[3];
  const float* Wk = (const float*)d_in[4];
  const float* Wv = (const float*)d_in[5];
  const float* Wo = (const float*)d_in[6];
  const int* mask = (const int*)d_in[7];

  char* ws = (char*)d_ws;
  const size_t MB = 1 << 20;
  const bool big = ws_size >= 41 * MB;

  dim3 ag(S_LEN / 64, 2 * NHEAD);  // (32, 32) = 1024 blocks

  if (big) {
    // Qb[0,8) Kb[8,16) VbT[16,24) Wt[24,30) WoT[30,32) Ob[32,40)
    short* Qb  = (short*)(ws);
    short* Kb  = (short*)(ws + 8 * MB);
    short* VbT = (short*)(ws + 16 * MB);
    short* WqT = (short*)(ws + 24 * MB);   // Wt = WqT|WkT|WvT contiguous
    short* WkT = (short*)(ws + 26 * MB);
    short* WvT = (short*)(ws + 28 * MB);
    short* WoT = (short*)(ws + 30 * MB);
    short* Ob  = (short*)(ws + 32 * MB);

    dim3 tgrid(16, 16, 4);
    wtrans<<<tgrid, 256, 0, stream>>>(Wq, Wk, Wv, Wo, WqT, WkT, WvT, WoT);

    dim3 gqkv(48, 32);  // N=3072, M=4096 -> 1536 blocks
    gemm4<<<gqkv, 256, 0, stream>>>(query, key, value, WqT, Qb, Kb, VbT);

    attn7<<<ag, 256, 0, stream>>>(Qb, Kb, VbT, mask, Ob);

    dim3 gqk(DM / 64, (2 * S_LEN) / 128);  // (16, 32) = 512
    gemm3<0><<<gqk, 256, 0, stream>>>(Ob, WoT, (float*)d_out, 2 * S_LEN, DM, DM);
  } else {
    short* Qb  = (short*)(ws);
    short* Kb  = (short*)(ws + 8 * MB);
    short* VbT = (short*)(ws + 16 * MB);
    short* WqT = (short*)(ws + 24 * MB);
    short* WkT = (short*)(ws + 26 * MB);
    short* WvT = (short*)(ws + 28 * MB);
    short* Ob  = (short*)(ws + 24 * MB);  // aliases dead WqT/WkT/WvT

    dim3 tgrid(16, 16, 3);
    wtrans<<<tgrid, 256, 0, stream>>>(Wq, Wk, Wv, Wo, WqT, WkT, WvT, WqT);

    dim3 gq(DM / 64, (2 * S_LEN) / 128);
    gemm2<0, 1, 3><<<gq, 256, 0, stream>>>(query, WqT, Qb, 2 * S_LEN, DM, DM);
    gemm2<0, 1, 1><<<gq, 256, 0, stream>>>(key,   WkT, Kb, 2 * S_LEN, DM, DM);
    dim3 gv((2 * S_LEN) / 64, DM / 128);
    gemm2<1, 0, 2><<<gv, 256, 0, stream>>>(WvT, value, VbT, DM, 2 * S_LEN, DM);

    attn7<<<ag, 256, 0, stream>>>(Qb, Kb, VbT, mask, Ob);

    gemm2<1, 2, 0><<<gq, 256, 0, stream>>>(Ob, Wo, (float*)d_out, 2 * S_LEN, DM, DM);
  }
}

// Round 8
// 138.100 us; speedup vs baseline: 1.3618x; 1.3618x over previous
//
#include <hip/hip_runtime.h>
#include <hip/hip_bf16.h>

typedef short bf16x8 __attribute__((ext_vector_type(8)));  // 8 bf16 (4 VGPRs)
typedef float f32x4 __attribute__((ext_vector_type(4)));

#define S_LEN 2048
#define NHEAD 16
#define DM 1024

#if __has_builtin(__builtin_amdgcn_exp2f)
#define EXP2(x) __builtin_amdgcn_exp2f(x)
#else
#define EXP2(x) exp2f(x)
#endif

__device__ __forceinline__ short f2bf(float f) {
  union { float f; unsigned u; } x; x.f = f;
  unsigned r = x.u + 0x7fffu + ((x.u >> 16) & 1u);  // RNE
  return (short)(r >> 16);
}

__device__ __forceinline__ unsigned cvt_pk_bf16(float lo, float hi) {
  unsigned r;
  asm("v_cvt_pk_bf16_f32 %0, %1, %2" : "=v"(r) : "v"(lo), "v"(hi));
  return r;
}

__device__ __forceinline__ void pl32swap(unsigned& a, unsigned& b) {
#if __has_builtin(__builtin_amdgcn_permlane32_swap)
  auto r = __builtin_amdgcn_permlane32_swap(a, b, false, false);
  a = r[0]; b = r[1];
#else
  asm volatile("v_permlane32_swap_b32 %0, %1" : "+v"(a), "+v"(b));
#endif
}
__device__ __forceinline__ void pl16swap(unsigned& a, unsigned& b) {
#if __has_builtin(__builtin_amdgcn_permlane16_swap)
  auto r = __builtin_amdgcn_permlane16_swap(a, b, false, false);
  a = r[0]; b = r[1];
#else
  asm volatile("v_permlane16_swap_b32 %0, %1" : "+v"(a), "+v"(b));
#endif
}

__device__ __forceinline__ void gload16(const void* g, void* l) {
  __builtin_amdgcn_global_load_lds(
      (const __attribute__((address_space(1))) void*)g,
      (__attribute__((address_space(3))) void*)l, 16, 0, 0);
}

// ---------------- weight transpose+convert; z==4: mask -> bf16 table Mb
__global__ __launch_bounds__(256) void wtrans(const float* __restrict__ Wq, const float* __restrict__ Wk,
                                              const float* __restrict__ Wv, const float* __restrict__ Wo,
                                              const int* __restrict__ mask,
                                              short* Tq, short* Tk, short* Tv, short* To, short* Mb) {
  const int z = blockIdx.z;
  const int tid = threadIdx.x;
  if (z == 4) {
    if (blockIdx.y == 0 && blockIdx.x < 16) {
      int i = blockIdx.x * 256 + tid;
      Mb[i] = mask[i] ? (short)0x3F80 : (short)0;  // bf16 1.0 / 0.0
    }
    return;
  }
  const float* W = (z == 0) ? Wq : (z == 1) ? Wk : (z == 2) ? Wv : Wo;
  short* T = (z == 0) ? Tq : (z == 1) ? Tk : (z == 2) ? Tv : To;
  __shared__ short Tl[64][72];
  const int k0 = blockIdx.x * 64, n0 = blockIdx.y * 64;
  const int r = tid >> 2, c0 = (tid & 3) * 16;
#pragma unroll
  for (int j = 0; j < 4; j++) {
    float4 v = *(const float4*)&W[(size_t)(k0 + r) * DM + n0 + c0 + 4 * j];
    Tl[r][c0 + 4 * j + 0] = f2bf(v.x);
    Tl[r][c0 + 4 * j + 1] = f2bf(v.y);
    Tl[r][c0 + 4 * j + 2] = f2bf(v.z);
    Tl[r][c0 + 4 * j + 3] = f2bf(v.w);
  }
  __syncthreads();
  bf16x8 o0, o1;
#pragma unroll
  for (int j = 0; j < 8; j++) { o0[j] = Tl[c0 + j][r]; o1[j] = Tl[c0 + 8 + j][r]; }
  *(bf16x8*)&T[(size_t)(n0 + r) * DM + k0 + c0] = o0;
  *(bf16x8*)&T[(size_t)(n0 + r) * DM + k0 + c0 + 8] = o1;
}

// ---------------- x f32 -> bf16 convert (3 tensors)
__global__ __launch_bounds__(256) void xcvt(const float* __restrict__ q, const float* __restrict__ k,
                                            const float* __restrict__ v,
                                            short* xq, short* xk, short* xv) {
  const int z = blockIdx.y;
  const float* src = (z == 0) ? q : (z == 1) ? k : v;
  short* dst = (z == 0) ? xq : (z == 1) ? xk : xv;
  const size_t base = ((size_t)blockIdx.x * 256 + threadIdx.x) * 16;
  float4 a = *(const float4*)&src[base];
  float4 b = *(const float4*)&src[base + 4];
  float4 c = *(const float4*)&src[base + 8];
  float4 d = *(const float4*)&src[base + 12];
  bf16x8 o0, o1;
  o0[0] = f2bf(a.x); o0[1] = f2bf(a.y); o0[2] = f2bf(a.z); o0[3] = f2bf(a.w);
  o0[4] = f2bf(b.x); o0[5] = f2bf(b.y); o0[6] = f2bf(b.z); o0[7] = f2bf(b.w);
  o1[0] = f2bf(c.x); o1[1] = f2bf(c.y); o1[2] = f2bf(c.z); o1[3] = f2bf(c.w);
  o1[4] = f2bf(d.x); o1[5] = f2bf(d.y); o1[6] = f2bf(d.z); o1[7] = f2bf(d.w);
  *(bf16x8*)&dst[base] = o0;
  *(bf16x8*)&dst[base + 8] = o1;
}

// ---------------- gemm3: all-bf16, gload_lds dbuf, swizzled LDS, XCD swizzle.
// CM: 0=f32 row-major, 1=bf16 [bh][s][64], 2=bf16 [bh][64][s],
//     3=CM1 scaled (Q), 4=CM2 with mask-zeroing (V for attn8)
template<int CM>
__global__ __launch_bounds__(256) void gemm3(const short* __restrict__ A, const short* __restrict__ Bt,
                                             void* __restrict__ Cp, int M, int N, int K,
                                             const int* __restrict__ mask) {
  __shared__ __align__(16) short Al[2][128 * 64];
  __shared__ __align__(16) short Bl[2][64 * 64];
  const int tid = threadIdx.x;
  const int lane = tid & 63, w = tid >> 6;
  const int wm = w >> 1, wn = w & 1;
  const int lr = lane & 15, g = lane >> 4;

  const int flat = blockIdx.y * gridDim.x + blockIdx.x;
  const int nwg = gridDim.x * gridDim.y;
  const int wid = (flat & 7) * (nwg >> 3) + (flat >> 3);
  const int bx = wid % gridDim.x, by = wid / gridDim.x;
  const int m0 = by * 128, n0 = bx * 64;

  f32x4 acc[4][2];
#pragma unroll
  for (int i = 0; i < 4; i++)
#pragma unroll
    for (int j = 0; j < 2; j++) acc[i][j] = (f32x4){0.f, 0.f, 0.f, 0.f};

  const int srow = lane >> 3;
  const int sch = (lane & 7) ^ (srow & 7);
  const short* gA = A + (size_t)(m0 + w * 32 + srow) * K + 8 * sch;
  const short* gB = Bt + (size_t)(n0 + w * 16 + srow) * K + 8 * sch;

#define STAGE(buf, kk)                                                              \
  do {                                                                              \
    _Pragma("unroll") for (int c = 0; c < 4; c++)                                   \
        gload16(gA + (size_t)c * 8 * K + (kk), &Al[buf][(w * 32 + c * 8) * 64]);    \
    _Pragma("unroll") for (int c = 0; c < 2; c++)                                   \
        gload16(gB + (size_t)c * 8 * K + (kk), &Bl[buf][(w * 16 + c * 8) * 64]);    \
  } while (0)

  const int nsteps = K >> 6;
  STAGE(0, 0);
  int buf = 0;
  for (int t = 0; t < nsteps; t++) {
    __syncthreads();
    if (t + 1 < nsteps) STAGE(buf ^ 1, (t + 1) << 6);
#pragma unroll
    for (int kc = 0; kc < 2; kc++) {
      bf16x8 af[4], bfr[2];
#pragma unroll
      for (int mt = 0; mt < 4; mt++) {
        int row = wm * 64 + mt * 16 + lr;
        af[mt] = *(const bf16x8*)&Al[buf][row * 64 + 8 * ((kc * 4 + g) ^ (lr & 7))];
      }
#pragma unroll
      for (int nt = 0; nt < 2; nt++) {
        int row = wn * 32 + nt * 16 + lr;
        bfr[nt] = *(const bf16x8*)&Bl[buf][row * 64 + 8 * ((kc * 4 + g) ^ (lr & 7))];
      }
      __builtin_amdgcn_s_setprio(1);
#pragma unroll
      for (int mt = 0; mt < 4; mt++)
#pragma unroll
        for (int nt = 0; nt < 2; nt++)
          acc[mt][nt] = __builtin_amdgcn_mfma_f32_16x16x32_bf16(af[mt], bfr[nt], acc[mt][nt], 0, 0, 0);
      __builtin_amdgcn_s_setprio(0);
    }
    buf ^= 1;
  }
#undef STAGE

#pragma unroll
  for (int mt = 0; mt < 4; mt++)
#pragma unroll
    for (int nt = 0; nt < 2; nt++) {
      if (CM == 0) {
#pragma unroll
        for (int r = 0; r < 4; r++) {
          int row = m0 + wm * 64 + mt * 16 + g * 4 + r;
          int col = n0 + wn * 32 + nt * 16 + lr;
          ((float*)Cp)[(size_t)row * N + col] = acc[mt][nt][r];
        }
      } else if (CM == 1 || CM == 3) {
        const float scale = (CM == 3) ? 0.18033688011f : 1.f;
#pragma unroll
        for (int r = 0; r < 4; r++) {
          int row = m0 + wm * 64 + mt * 16 + g * 4 + r;
          int col = n0 + wn * 32 + nt * 16 + lr;
          int b = row >> 11, s = row & (S_LEN - 1);
          int h = col >> 6, d = col & 63;
          ((short*)Cp)[(((size_t)(b * NHEAD + h)) * S_LEN + s) * 64 + d] = f2bf(acc[mt][nt][r] * scale);
        }
      } else {  // CM 2/4: row = dmodel(d,h), col = token(b,s); 4 r's = 4 consecutive... no:
        // here r indexes ROW (dmodel); col fixed per lane. Write scalar per r.
#pragma unroll
        for (int r = 0; r < 4; r++) {
          int row = m0 + wm * 64 + mt * 16 + g * 4 + r;
          int col = n0 + wn * 32 + nt * 16 + lr;
          int h = row >> 6, d = row & 63;
          int b = col >> 11, s = col & (S_LEN - 1);
          float v = acc[mt][nt][r];
          if (CM == 4) v = mask[b * S_LEN + s] ? v : 0.f;
          ((short*)Cp)[(((size_t)(b * NHEAD + h)) * 64 + d) * S_LEN + s] = f2bf(v);
        }
      }
    }
}

// ---------------- gemm2 (fallback)
template<int AM, int BMODE, int CM>
__global__ __launch_bounds__(256) void gemm2(const void* __restrict__ Ap, const void* __restrict__ Bp,
                                             void* __restrict__ Cp, int M, int N, int K) {
  __shared__ __align__(16) short Al[128][72];
  __shared__ __align__(16) short Bl[64][72];
  const int tid = threadIdx.x;
  const int lane = tid & 63, w = tid >> 6;
  const int wm = w >> 1, wn = w & 1;
  const int lr = lane & 15, g = lane >> 4;
  const int m0 = blockIdx.y * 128, n0 = blockIdx.x * 64;

  f32x4 acc[4][2];
#pragma unroll
  for (int i = 0; i < 4; i++)
#pragma unroll
    for (int j = 0; j < 2; j++) acc[i][j] = (f32x4){0.f, 0.f, 0.f, 0.f};

  const int ar = tid >> 1, ac = (tid & 1) * 32;
  const int br = tid >> 2, bc = (tid & 3) * 16;

  float4 la[8]; bf16x8 la8[4];
  float4 lb[4]; bf16x8 lb8[2];

#define LOADA(kk)                                                                        \
  do {                                                                                   \
    if (AM == 0) {                                                                       \
      const float* A = (const float*)Ap;                                                 \
      _Pragma("unroll") for (int j = 0; j < 8; j++)                                      \
          la[j] = *(const float4*)&A[(size_t)(m0 + ar) * K + (kk) + ac + 4 * j];         \
    } else {                                                                             \
      const short* A = (const short*)Ap;                                                 \
      _Pragma("unroll") for (int j = 0; j < 4; j++)                                      \
          la8[j] = *(const bf16x8*)&A[(size_t)(m0 + ar) * K + (kk) + ac + 8 * j];        \
    }                                                                                    \
  } while (0)

#define LOADB(kk)                                                                        \
  do {                                                                                   \
    if (BMODE == 0) {                                                                    \
      const float* B = (const float*)Bp;                                                 \
      _Pragma("unroll") for (int j = 0; j < 4; j++)                                      \
          lb[j] = *(const float4*)&B[(size_t)(n0 + br) * K + (kk) + bc + 4 * j];         \
    } else if (BMODE == 1) {                                                             \
      const short* B = (const short*)Bp;                                                 \
      _Pragma("unroll") for (int j = 0; j < 2; j++)                                      \
          lb8[j] = *(const bf16x8*)&B[(size_t)(n0 + br) * K + (kk) + bc + 8 * j];        \
    } else {                                                                             \
      const float* B = (const float*)Bp;                                                 \
      _Pragma("unroll") for (int j = 0; j < 4; j++)                                      \
          lb[j] = *(const float4*)&B[(size_t)((kk) + br) * N + n0 + bc + 4 * j];         \
    }                                                                                    \
  } while (0)

  const int nsteps = K >> 6;
  LOADA(0); LOADB(0);

  for (int t = 0; t < nsteps; t++) {
    __syncthreads();
    if (AM == 0) {
#pragma unroll
      for (int j = 0; j < 4; j++) {
        float4 v0 = la[2 * j], v1 = la[2 * j + 1];
        bf16x8 tt;
        tt[0] = f2bf(v0.x); tt[1] = f2bf(v0.y); tt[2] = f2bf(v0.z); tt[3] = f2bf(v0.w);
        tt[4] = f2bf(v1.x); tt[5] = f2bf(v1.y); tt[6] = f2bf(v1.z); tt[7] = f2bf(v1.w);
        *(bf16x8*)&Al[ar][ac + 8 * j] = tt;
      }
    } else {
#pragma unroll
      for (int j = 0; j < 4; j++) *(bf16x8*)&Al[ar][ac + 8 * j] = la8[j];
    }
    if (BMODE == 0) {
#pragma unroll
      for (int j = 0; j < 2; j++) {
        float4 v0 = lb[2 * j], v1 = lb[2 * j + 1];
        bf16x8 tt;
        tt[0] = f2bf(v0.x); tt[1] = f2bf(v0.y); tt[2] = f2bf(v0.z); tt[3] = f2bf(v0.w);
        tt[4] = f2bf(v1.x); tt[5] = f2bf(v1.y); tt[6] = f2bf(v1.z); tt[7] = f2bf(v1.w);
        *(bf16x8*)&Bl[br][bc + 8 * j] = tt;
      }
    } else if (BMODE == 1) {
#pragma unroll
      for (int j = 0; j < 2; j++) *(bf16x8*)&Bl[br][bc + 8 * j] = lb8[j];
    } else {
#pragma unroll
      for (int j = 0; j < 4; j++) {
        float4 v = lb[j];
        Bl[bc + 4 * j + 0][br] = f2bf(v.x);
        Bl[bc + 4 * j + 1][br] = f2bf(v.y);
        Bl[bc + 4 * j + 2][br] = f2bf(v.z);
        Bl[bc + 4 * j + 3][br] = f2bf(v.w);
      }
    }
    __syncthreads();
    if (t + 1 < nsteps) { LOADA((t + 1) << 6); LOADB((t + 1) << 6); }
#pragma unroll
    for (int kc = 0; kc < 2; kc++) {
      bf16x8 af[4], bfr[2];
#pragma unroll
      for (int mt = 0; mt < 4; mt++) af[mt] = *(const bf16x8*)&Al[wm * 64 + mt * 16 + lr][kc * 32 + g * 8];
#pragma unroll
      for (int nt = 0; nt < 2; nt++) bfr[nt] = *(const bf16x8*)&Bl[wn * 32 + nt * 16 + lr][kc * 32 + g * 8];
#pragma unroll
      for (int mt = 0; mt < 4; mt++)
#pragma unroll
        for (int nt = 0; nt < 2; nt++)
          acc[mt][nt] = __builtin_amdgcn_mfma_f32_16x16x32_bf16(af[mt], bfr[nt], acc[mt][nt], 0, 0, 0);
    }
  }
#undef LOADA
#undef LOADB

#pragma unroll
  for (int mt = 0; mt < 4; mt++)
#pragma unroll
    for (int nt = 0; nt < 2; nt++)
#pragma unroll
      for (int r = 0; r < 4; r++) {
        int row = m0 + wm * 64 + mt * 16 + g * 4 + r;
        int col = n0 + wn * 32 + nt * 16 + lr;
        if (CM == 0) {
          ((float*)Cp)[(size_t)row * N + col] = acc[mt][nt][r];
        } else if (CM == 1 || CM == 3) {
          float v = (CM == 3) ? acc[mt][nt][r] * 0.18033688011f : acc[mt][nt][r];
          int b = row >> 11, s = row & (S_LEN - 1);
          int h = col >> 6, d = col & 63;
          ((short*)Cp)[(((size_t)(b * NHEAD + h)) * S_LEN + s) * 64 + d] = f2bf(v);
        } else {
          int h = row >> 6, d = row & 63;
          int b = col >> 11, s = col & (S_LEN - 1);
          ((short*)Cp)[(((size_t)(b * NHEAD + h)) * 64 + d) * S_LEN + s] = f2bf(acc[mt][nt][r]);
        }
      }
}

// ---------------- Flash attention v8: QBLK=64 shell + mask-free inner loop.
// V rows pre-zeroed for masked keys (gemm3<4>); row-sum via MFMA vs bf16 mask
// table Mb -> no per-tile bias/cndmask/adds, no epilogue shuffles.
__global__ __launch_bounds__(256, 4) void attn8(const short* __restrict__ Qb,
                                                const short* __restrict__ Kb,
                                                const short* __restrict__ VbT,
                                                const short* __restrict__ Mb,
                                                short* __restrict__ Ob) {
  __shared__ __align__(16) short Kl[2][64][64];
  __shared__ __align__(16) short Vl[2][64][64];

  const int tid = threadIdx.x;
  const int lane = tid & 63, w = tid >> 6;
  const int lr = lane & 15, g = lane >> 4;

  const int flat = blockIdx.y * gridDim.x + blockIdx.x;
  const int wid = (flat & 7) * 128 + (flat >> 3);
  const int qblk = wid & 31, bh = wid >> 5;
  const int b = bh >> 4, h = bh & 15;
  const int qbase = qblk * 64;
  const size_t hoff = (size_t)bh * S_LEN * 64;

  bf16x8 qf[2];
#pragma unroll
  for (int kh = 0; kh < 2; kh++)
    qf[kh] = *(const bf16x8*)&Qb[hoff + (size_t)(qbase + w * 16 + lr) * 64 + kh * 32 + g * 8];

  f32x4 o_acc[4];
  f32x4 o_l = (f32x4){0.f, 0.f, 0.f, 0.f};
#pragma unroll
  for (int dg = 0; dg < 4; dg++) o_acc[dg] = (f32x4){0.f, 0.f, 0.f, 0.f};

  const short* Mbb = Mb + b * S_LEN;
  const int srow = lane >> 3;
  const int sch = (lane & 7) ^ (srow & 7);
  const short* gK = Kb + hoff + (size_t)(w * 16 + srow) * 64 + 8 * sch;
  const short* gV = VbT + hoff + (size_t)(w * 16 + srow) * S_LEN + 8 * sch;

#define STAGEKV(buf, kb)                                                         \
  do {                                                                           \
    _Pragma("unroll") for (int c = 0; c < 2; c++)                                \
        gload16(gK + (size_t)(kb + c * 8) * 64, &Kl[buf][w * 16 + c * 8][0]);    \
    _Pragma("unroll") for (int c = 0; c < 2; c++)                                \
        gload16(gV + (size_t)c * 8 * S_LEN + (kb), &Vl[buf][w * 16 + c * 8][0]); \
  } while (0)

  const int NT = S_LEN / 64;
  STAGEKV(0, 0);
  int buf = 0;

  for (int t = 0; t < NT; t++) {
    const int kb = t * 64;
    bf16x8 mf0 = *(const bf16x8*)&Mbb[kb + g * 8];        // mask frag (B-operand)
    bf16x8 mf1 = *(const bf16x8*)&Mbb[kb + 32 + g * 8];
    __syncthreads();
    if (t + 1 < NT) STAGEKV(buf ^ 1, kb + 64);

    f32x4 s[4];
#pragma unroll
    for (int nt = 0; nt < 4; nt++) s[nt] = (f32x4){0.f, 0.f, 0.f, 0.f};
    __builtin_amdgcn_s_setprio(1);
#pragma unroll
    for (int nt = 0; nt < 4; nt++) {
      bf16x8 k0 = *(const bf16x8*)&Kl[buf][nt * 16 + lr][8 * (g ^ (lr & 7))];
      bf16x8 k1 = *(const bf16x8*)&Kl[buf][nt * 16 + lr][8 * ((4 + g) ^ (lr & 7))];
      s[nt] = __builtin_amdgcn_mfma_f32_16x16x32_bf16(k0, qf[0], s[nt], 0, 0, 0);
      s[nt] = __builtin_amdgcn_mfma_f32_16x16x32_bf16(k1, qf[1], s[nt], 0, 0, 0);
    }
    __builtin_amdgcn_s_setprio(0);

    unsigned W0[4], W1[4];
#pragma unroll
    for (int nt = 0; nt < 4; nt++) {
      float p0 = EXP2(s[nt][0]);
      float p1 = EXP2(s[nt][1]);
      float p2 = EXP2(s[nt][2]);
      float p3 = EXP2(s[nt][3]);
      W0[nt] = cvt_pk_bf16(p0, p1);
      W1[nt] = cvt_pk_bf16(p2, p3);
    }

    bf16x8 pf[2];
#pragma unroll
    for (int kh = 0; kh < 2; kh++) {
      unsigned a0 = W0[2 * kh], b0 = W0[2 * kh + 1];
      unsigned a1 = W1[2 * kh], b1 = W1[2 * kh + 1];
      pl32swap(a0, b0); pl16swap(a0, b0);
      pl32swap(a1, b1); pl16swap(a1, b1);
      union { unsigned u[4]; bf16x8 v; } pk;
      pk.u[0] = a0; pk.u[1] = a1; pk.u[2] = b0; pk.u[3] = b1;
      pf[kh] = pk.v;
    }

    __builtin_amdgcn_s_setprio(1);
#pragma unroll
    for (int dg = 0; dg < 4; dg++) {
      bf16x8 v0 = *(const bf16x8*)&Vl[buf][dg * 16 + lr][8 * (g ^ (lr & 7))];
      bf16x8 v1 = *(const bf16x8*)&Vl[buf][dg * 16 + lr][8 * ((4 + g) ^ (lr & 7))];
      o_acc[dg] = __builtin_amdgcn_mfma_f32_16x16x32_bf16(pf[0], v0, o_acc[dg], 0, 0, 0);
      o_acc[dg] = __builtin_amdgcn_mfma_f32_16x16x32_bf16(pf[1], v1, o_acc[dg], 0, 0, 0);
    }
    o_l = __builtin_amdgcn_mfma_f32_16x16x32_bf16(pf[0], mf0, o_l, 0, 0, 0);
    o_l = __builtin_amdgcn_mfma_f32_16x16x32_bf16(pf[1], mf1, o_l, 0, 0, 0);
    __builtin_amdgcn_s_setprio(0);
    buf ^= 1;
  }
#undef STAGEKV

#pragma unroll
  for (int r = 0; r < 4; r++) {
    float inv = 1.f / o_l[r];
    int qr = qbase + w * 16 + 4 * g + r;
#pragma unroll
    for (int dg = 0; dg < 4; dg++) {
      int col = h * 64 + dg * 16 + lr;
      Ob[((size_t)b * S_LEN + qr) * DM + col] = f2bf(o_acc[dg][r] * inv);
    }
  }
}

// ---------------- attn7 (self-masking, fallback path)
__global__ __launch_bounds__(256, 4) void attn7(const short* __restrict__ Qb,
                                                const short* __restrict__ Kb,
                                                const short* __restrict__ VbT,
                                                const int* __restrict__ mask,
                                                short* __restrict__ Ob) {
  __shared__ __align__(16) short Kl[2][64][64];
  __shared__ __align__(16) short Vl[2][64][64];

  const int tid = threadIdx.x;
  const int lane = tid & 63, w = tid >> 6;
  const int lr = lane & 15, g = lane >> 4;

  const int flat = blockIdx.y * gridDim.x + blockIdx.x;
  const int wid = (flat & 7) * 128 + (flat >> 3);
  const int qblk = wid & 31, bh = wid >> 5;
  const int b = bh >> 4, h = bh & 15;
  const int qbase = qblk * 64;
  const size_t hoff = (size_t)bh * S_LEN * 64;

  bf16x8 qf[2];
#pragma unroll
  for (int kh = 0; kh < 2; kh++)
    qf[kh] = *(const bf16x8*)&Qb[hoff + (size_t)(qbase + w * 16 + lr) * 64 + kh * 32 + g * 8];

  f32x4 o_acc[4];
  float lsum = 0.f;
#pragma unroll
  for (int dg = 0; dg < 4; dg++) o_acc[dg] = (f32x4){0.f, 0.f, 0.f, 0.f};

  const int* maskb = mask + b * S_LEN;
  const int srow = lane >> 3;
  const int sch = (lane & 7) ^ (srow & 7);
  const short* gK = Kb + hoff + (size_t)(w * 16 + srow) * 64 + 8 * sch;
  const short* gV = VbT + hoff + (size_t)(w * 16 + srow) * S_LEN + 8 * sch;

#define STAGEKV(buf, kb)                                                         \
  do {                                                                           \
    _Pragma("unroll") for (int c = 0; c < 2; c++)                                \
        gload16(gK + (size_t)(kb + c * 8) * 64, &Kl[buf][w * 16 + c * 8][0]);    \
    _Pragma("unroll") for (int c = 0; c < 2; c++)                                \
        gload16(gV + (size_t)c * 8 * S_LEN + (kb), &Vl[buf][w * 16 + c * 8][0]); \
  } while (0)

  const int NT = S_LEN / 64;
  STAGEKV(0, 0);
  int buf = 0;

  for (int t = 0; t < NT; t++) {
    const int kb = t * 64;
    __syncthreads();
    if (t + 1 < NT) STAGEKV(buf ^ 1, kb + 64);

    float bias[4][4];
#pragma unroll
    for (int nt = 0; nt < 4; nt++) {
      int4 mv = *(const int4*)&maskb[kb + nt * 16 + 4 * g];
      bias[nt][0] = mv.x ? 0.f : -1e30f;
      bias[nt][1] = mv.y ? 0.f : -1e30f;
      bias[nt][2] = mv.z ? 0.f : -1e30f;
      bias[nt][3] = mv.w ? 0.f : -1e30f;
    }

    f32x4 s[4];
#pragma unroll
    for (int nt = 0; nt < 4; nt++) s[nt] = (f32x4){0.f, 0.f, 0.f, 0.f};
    __builtin_amdgcn_s_setprio(1);
#pragma unroll
    for (int nt = 0; nt < 4; nt++) {
      bf16x8 k0 = *(const bf16x8*)&Kl[buf][nt * 16 + lr][8 * (g ^ (lr & 7))];
      bf16x8 k1 = *(const bf16x8*)&Kl[buf][nt * 16 + lr][8 * ((4 + g) ^ (lr & 7))];
      s[nt] = __builtin_amdgcn_mfma_f32_16x16x32_bf16(k0, qf[0], s[nt], 0, 0, 0);
      s[nt] = __builtin_amdgcn_mfma_f32_16x16x32_bf16(k1, qf[1], s[nt], 0, 0, 0);
    }
    __builtin_amdgcn_s_setprio(0);

    unsigned W0[4], W1[4];
#pragma unroll
    for (int nt = 0; nt < 4; nt++) {
      float p0 = EXP2(s[nt][0] + bias[nt][0]);
      float p1 = EXP2(s[nt][1] + bias[nt][1]);
      float p2 = EXP2(s[nt][2] + bias[nt][2]);
      float p3 = EXP2(s[nt][3] + bias[nt][3]);
      lsum += (p0 + p1) + (p2 + p3);
      W0[nt] = cvt_pk_bf16(p0, p1);
      W1[nt] = cvt_pk_bf16(p2, p3);
    }

    bf16x8 pf[2];
#pragma unroll
    for (int kh = 0; kh < 2; kh++) {
      unsigned a0 = W0[2 * kh], b0 = W0[2 * kh + 1];
      unsigned a1 = W1[2 * kh], b1 = W1[2 * kh + 1];
      pl32swap(a0, b0); pl16swap(a0, b0);
      pl32swap(a1, b1); pl16swap(a1, b1);
      union { unsigned u[4]; bf16x8 v; } pk;
      pk.u[0] = a0; pk.u[1] = a1; pk.u[2] = b0; pk.u[3] = b1;
      pf[kh] = pk.v;
    }

    __builtin_amdgcn_s_setprio(1);
#pragma unroll
    for (int dg = 0; dg < 4; dg++) {
      bf16x8 v0 = *(const bf16x8*)&Vl[buf][dg * 16 + lr][8 * (g ^ (lr & 7))];
      bf16x8 v1 = *(const bf16x8*)&Vl[buf][dg * 16 + lr][8 * ((4 + g) ^ (lr & 7))];
      o_acc[dg] = __builtin_amdgcn_mfma_f32_16x16x32_bf16(pf[0], v0, o_acc[dg], 0, 0, 0);
      o_acc[dg] = __builtin_amdgcn_mfma_f32_16x16x32_bf16(pf[1], v1, o_acc[dg], 0, 0, 0);
    }
    __builtin_amdgcn_s_setprio(0);
    buf ^= 1;
  }
#undef STAGEKV

  {
    float l = lsum;
    l += __shfl_xor(l, 16);
    l += __shfl_xor(l, 32);
    float inv = 1.f / l;
    float invq[4];
#pragma unroll
    for (int r = 0; r < 4; r++) invq[r] = __shfl(inv, 4 * g + r);
#pragma unroll
    for (int dg = 0; dg < 4; dg++)
#pragma unroll
      for (int r = 0; r < 4; r++) {
        int qr = qbase + w * 16 + 4 * g + r;
        int col = h * 64 + dg * 16 + lr;
        Ob[((size_t)b * S_LEN + qr) * DM + col] = f2bf(o_acc[dg][r] * invq[r]);
      }
  }
}

extern "C" void kernel_launch(void* const* d_in, const int* in_sizes, int n_in,
                              void* d_out, int out_size, void* d_ws, size_t ws_size,
                              hipStream_t stream) {
  const float* query = (const float*)d_in[0];
  const float* key   = (const float*)d_in[1];
  const float* value = (const float*)d_in[2];
  const float* Wq = (const float*)d_in[3];
  const float* Wk = (const float*)d_in[4];
  const float* Wv = (const float*)d_in[5];
  const float* Wo = (const float*)d_in[6];
  const int* mask = (const int*)d_in[7];

  char* ws = (char*)d_ws;
  const size_t MB = 1 << 20;
  const bool big = ws_size >= 41 * MB;

  dim3 ag(S_LEN / 64, 2 * NHEAD);  // (32, 32) = 1024 blocks

  if (big) {
    // xq[0,8) xk[8,16) xv[16,24) Wt[24,30) WoT[30,32) Qb[32,40) Mb[40,+8KB)
    // Kb -> old xq slot (consumed), VbT -> old xk slot, Ob -> old xv slot.
    short* xq  = (short*)(ws);
    short* xk  = (short*)(ws + 8 * MB);
    short* xv  = (short*)(ws + 16 * MB);
    short* WqT = (short*)(ws + 24 * MB);
    short* WkT = (short*)(ws + 26 * MB);
    short* WvT = (short*)(ws + 28 * MB);
    short* WoT = (short*)(ws + 30 * MB);
    short* Qb  = (short*)(ws + 32 * MB);
    short* Mb  = (short*)(ws + 40 * MB);
    short* Kb  = xq;
    short* VbT = xk;
    short* Ob  = xv;

    dim3 tgrid(16, 16, 5);
    wtrans<<<tgrid, 256, 0, stream>>>(Wq, Wk, Wv, Wo, mask, WqT, WkT, WvT, WoT, Mb);
    dim3 cg(1024, 3);
    xcvt<<<cg, 256, 0, stream>>>(query, key, value, xq, xk, xv);

    dim3 gqk(DM / 64, (2 * S_LEN) / 128);  // (16, 32) = 512
    gemm3<3><<<gqk, 256, 0, stream>>>(xq, WqT, Qb, 2 * S_LEN, DM, DM, mask);
    gemm3<1><<<gqk, 256, 0, stream>>>(xk, WkT, Kb, 2 * S_LEN, DM, DM, mask);
    dim3 gv((2 * S_LEN) / 64, DM / 128);   // (64, 8) = 512
    gemm3<4><<<gv, 256, 0, stream>>>(WvT, xv, VbT, DM, 2 * S_LEN, DM, mask);  // V^T, mask-zeroed
    // NOTE: gemm3 B-operand must be [n][k]; here B = xv is [token][k] and
    // N-dim = tokens -> Bt rows are tokens ✓ (same as round-6 gemm3<2> call).

    attn8<<<ag, 256, 0, stream>>>(Qb, Kb, VbT, Mb, Ob);

    gemm3<0><<<gqk, 256, 0, stream>>>(Ob, WoT, (float*)d_out, 2 * S_LEN, DM, DM, mask);
  } else {
    short* Qb  = (short*)(ws);
    short* Kb  = (short*)(ws + 8 * MB);
    short* VbT = (short*)(ws + 16 * MB);
    short* WqT = (short*)(ws + 24 * MB);
    short* WkT = (short*)(ws + 26 * MB);
    short* WvT = (short*)(ws + 28 * MB);
    short* Ob  = (short*)(ws + 24 * MB);

    dim3 tgrid(16, 16, 3);
    wtrans<<<tgrid, 256, 0, stream>>>(Wq, Wk, Wv, Wo, mask, WqT, WkT, WvT, WqT, WqT);

    dim3 gq(DM / 64, (2 * S_LEN) / 128);
    gemm2<0, 1, 3><<<gq, 256, 0, stream>>>(query, WqT, Qb, 2 * S_LEN, DM, DM);
    gemm2<0, 1, 1><<<gq, 256, 0, stream>>>(key,   WkT, Kb, 2 * S_LEN, DM, DM);
    dim3 gv((2 * S_LEN) / 64, DM / 128);
    gemm2<1, 0, 2><<<gv, 256, 0, stream>>>(WvT, value, VbT, DM, 2 * S_LEN, DM);

    attn7<<<ag, 256, 0, stream>>>(Qb, Kb, VbT, mask, Ob);

    gemm2<1, 2, 0><<<gq, 256, 0, stream>>>(Ob, Wo, (float*)d_out, 2 * S_LEN, DM, DM);
  }
}